// Round 4
// baseline (426.919 us; speedup 1.0000x reference)
//
#include <hip/hip_runtime.h>

// DCNv4 3D — round 4 (= round 3 + cvt_pkrtz type fix):
//  * internal dtype f16 (fma_mix-friendly unpack, same MFMA rate, better mantissa)
//  * om region re-laid-out as [G][K][4] (od,oh,ow,m) -> one 8B load per lane
//  * f16-packed butterfly reduce (4 words instead of 8)
//  * unified permuted bias -> branchless GEMM epilogue

typedef _Float16 f16;
typedef _Float16 f16x8 __attribute__((ext_vector_type(8)));
typedef _Float16 f16x4 __attribute__((ext_vector_type(4)));
typedef _Float16 f16x2 __attribute__((ext_vector_type(2)));
typedef float    f32x4 __attribute__((ext_vector_type(4)));

#define NB 2
#define DD 32
#define HH 32
#define WW 32
#define CC 128
#define GG 8
#define CG 16
#define KPTS 27
#define LL (DD*HH*WW)     // 32768
#define MM (NB*LL)        // 65536
#define OMD 864
#define PXW (CC + OMD)    // 992

// byte strides inside pxo (f16)
#define ROWB (PXW*2)          // 1984 bytes per flat-position step
#define YB   (WW*ROWB)        // 63488
#define ZB   (HH*WW*ROWB)     // 2031616

__device__ __forceinline__ f16x2 pkrtz(float a, float b) {
  return __builtin_bit_cast(f16x2, __builtin_amdgcn_cvt_pkrtz(a, b));
}

// ---- build wcat [992,128] f16: value_w rows ++ permuted offmask_w rows ----
// om new layout (within group g): row 128 + g*108 + k*4 + j, j=0..2 offsets,
// j=3 mask; source row g*108 + (j<3 ? k*3+j : 81+k).
__global__ __launch_bounds__(256) void build_wcat(const float* __restrict__ vw,
                                                  const float* __restrict__ ow,
                                                  f16* __restrict__ wcat) {
  int t = blockIdx.x * 256 + threadIdx.x;   // PXW*32 threads
  if (t >= PXW * 32) return;
  int p = t >> 5, c4 = (t & 31) * 4;
  const float* src;
  if (p < CC) {
    src = vw + (size_t)p * CC;
  } else {
    int q = p - CC, g = q / 108, r = q % 108, k = r >> 2, j = r & 3;
    src = ow + (size_t)(g * 108 + (j < 3 ? k * 3 + j : 81 + k)) * CC;
  }
  float4 v = *(const float4*)(src + c4);
  f16x4 o = {(f16)v.x, (f16)v.y, (f16)v.z, (f16)v.w};
  *(f16x4*)(wcat + (size_t)p * CC + c4) = o;
}

__global__ __launch_bounds__(256) void build_bias(const float* __restrict__ vb,
                                                  const float* __restrict__ ob,
                                                  float* __restrict__ pbias) {
  int p = blockIdx.x * 256 + threadIdx.x;
  if (p >= PXW) return;
  float v;
  if (p < CC) v = vb[p];
  else {
    int q = p - CC, g = q / 108, r = q % 108, k = r >> 2, j = r & 3;
    v = ob[g * 108 + (j < 3 ? k * 3 + j : 81 + k)];
  }
  pbias[p] = v;
}

__global__ __launch_bounds__(256) void cvt_f2h(const float* __restrict__ in,
                                               f16* __restrict__ out, int n4) {
  int i = blockIdx.x * blockDim.x + threadIdx.x;
  if (i >= n4) return;
  float4 v = ((const float4*)in)[i];
  f16x4 o = {(f16)v.x, (f16)v.y, (f16)v.z, (f16)v.w};
  ((f16x4*)out)[i] = o;
}

// ---------------- GEMM: out[M,NCOLS] = A[M,128] @ B[NCOLS,128]^T + bias ---
// Block = 256 thr = 4 waves; block owns 64 rows. A-fragments register-cached;
// loop over NCOLS/32 col-tiles.
template<bool AF32, bool OUTF32, int NCOLS>
__global__ __launch_bounds__(256) void gemm_k128(
    const void* __restrict__ Ain, const f16* __restrict__ B,
    const float* __restrict__ bias, void* __restrict__ outp) {
  const int w    = threadIdx.x >> 6;
  const int lane = threadIdx.x & 63;
  const int rowBase = blockIdx.x * 64 + w * 16;
  const int r  = lane & 15;
  const int kg = lane >> 4;

  f16x8 a[4];
  if (AF32) {
    const float* A = (const float*)Ain + (size_t)(rowBase + r) * CC + kg * 8;
#pragma unroll
    for (int kk = 0; kk < 4; ++kk) {
      float4 lo = *(const float4*)(A + kk * 32);
      float4 hi = *(const float4*)(A + kk * 32 + 4);
      f16x8 t;
      t[0] = (f16)lo.x; t[1] = (f16)lo.y; t[2] = (f16)lo.z; t[3] = (f16)lo.w;
      t[4] = (f16)hi.x; t[5] = (f16)hi.y; t[6] = (f16)hi.z; t[7] = (f16)hi.w;
      a[kk] = t;
    }
  } else {
    const f16* A = (const f16*)Ain + (size_t)(rowBase + r) * CC + kg * 8;
#pragma unroll
    for (int kk = 0; kk < 4; ++kk) a[kk] = *(const f16x8*)(A + kk * 32);
  }

  for (int ct = 0; ct < NCOLS / 32; ++ct) {
    const int colBase = ct * 32;
    const f16* Bp = B + (unsigned)(colBase + r) * CC + kg * 8;
    f32x4 acc0 = {0.f, 0.f, 0.f, 0.f};
    f32x4 acc1 = {0.f, 0.f, 0.f, 0.f};
#pragma unroll
    for (int kk = 0; kk < 4; ++kk) {
      f16x8 b0 = *(const f16x8*)(Bp + kk * 32);
      f16x8 b1 = *(const f16x8*)(Bp + 16 * CC + kk * 32);
      acc0 = __builtin_amdgcn_mfma_f32_16x16x32_f16(a[kk], b0, acc0, 0, 0, 0);
      acc1 = __builtin_amdgcn_mfma_f32_16x16x32_f16(a[kk], b1, acc1, 0, 0, 0);
    }
    const int c0 = colBase + r;
    const int c1 = c0 + 16;
    const float bv0 = bias[c0];
    const float bv1 = bias[c1];
    const int drow = rowBase + kg * 4;
#pragma unroll
    for (int i = 0; i < 4; ++i) {
      float v0 = acc0[i] + bv0;
      float v1 = acc1[i] + bv1;
      unsigned ro = (unsigned)(drow + i) * NCOLS;
      if (OUTF32) {
        ((float*)outp)[ro + c0] = v0;
        ((float*)outp)[ro + c1] = v1;
      } else {
        ((f16*)outp)[ro + c0] = (f16)v0;
        ((f16*)outp)[ro + c1] = (f16)v1;
      }
    }
  }
}

// ---------------- DCNv4 sampling core v3 (f16) ----------------
// One wave per (row, g). lane = ks*2 + ch; ks = k-slot (0..31, 27 active),
// ch = channel half (8 ch, 16B per gather). om: one 8B load per lane.
__global__ __launch_bounds__(256) void dcn_core(const f16* __restrict__ pxo,
                                                f16* __restrict__ y) {
  const int wid  = blockIdx.x * 4 + (threadIdx.x >> 6);
  const int lane = threadIdx.x & 63;
  const int row  = wid >> 3;
  const int g    = wid & 7;
  const int ks   = lane >> 1;
  const int ch   = lane & 1;
  const int l    = row & (LL - 1);
  const int nb   = row >> 15;
  const int ldz  = l >> 10;
  const int lhy  = (l >> 5) & 31;
  const int lwx  = l & 31;

  const int kc = (ks < KPTS) ? ks : KPTS - 1;
  const int kd = kc / 9, kh = (kc / 3) % 3, kw = kc % 3;

  // om: [G][K][4] (od,oh,ow,m) -> single aligned 8B load
  const char* omb = (const char*)pxo + ((size_t)row * PXW + CC + g * 108) * 2;
  uint2 ld = *(const uint2*)(omb + kc * 8);
  f16x2 o01 = __builtin_bit_cast(f16x2, ld.x);
  f16x2 o23 = __builtin_bit_cast(f16x2, ld.y);
  float od = (float)o01[0], oh = (float)o01[1], ow = (float)o23[0];
  float m  = (ks < KPTS) ? (float)o23[1] : 0.f;

  float pd = (float)(ldz + kd - 1) + od;
  float ph = (float)(lhy + kh - 1) + oh;
  float pw = (float)(lwx + kw - 1) + ow;
  float fd = floorf(pd), fh = floorf(ph), fw = floorf(pw);
  float td = pd - fd,    th = ph - fh,    tw = pw - fw;
  int   id = (int)fd,    ih = (int)fh,    iw = (int)fw;

  // per-dim weights with validity (mask folded into z)
  float wz0 = ((unsigned)id       < DD) ? (1.f - td) * m : 0.f;
  float wz1 = ((unsigned)(id + 1) < DD) ? td * m         : 0.f;
  float wy0 = ((unsigned)ih       < HH) ? (1.f - th)     : 0.f;
  float wy1 = ((unsigned)(ih + 1) < HH) ? th             : 0.f;
  float wx0 = ((unsigned)iw       < WW) ? (1.f - tw)     : 0.f;
  float wx1 = ((unsigned)(iw + 1) < WW) ? tw             : 0.f;

  // per-dim clamped byte offsets
  const int zc0 = min(max(id,     0), DD - 1) * ZB;
  const int zc1 = min(max(id + 1, 0), DD - 1) * ZB;
  const int yc0 = min(max(ih,     0), HH - 1) * YB;
  const int yc1 = min(max(ih + 1, 0), HH - 1) * YB;
  const int xc0 = min(max(iw,     0), WW - 1) * ROWB + ch * 16;
  const int xc1 = min(max(iw + 1, 0), WW - 1) * ROWB + ch * 16;

  const int boff = __builtin_amdgcn_readfirstlane(nb * (LL * ROWB) + g * (CG * 2));
  const char* basep = (const char*)pxo + boff;

  // zy products once
  float wzy00 = wz0 * wy0, wzy01 = wz0 * wy1;
  float wzy10 = wz1 * wy0, wzy11 = wz1 * wy1;

  uint4 q[8];
  float wg[8];
#pragma unroll
  for (int c = 0; c < 8; ++c) {
    const int cz = (c >> 2) & 1, cy = (c >> 1) & 1, cx = c & 1;
    const int voff = (cz ? zc1 : zc0) + (cy ? yc1 : yc0) + (cx ? xc1 : xc0);
    float wzy = cz ? (cy ? wzy11 : wzy10) : (cy ? wzy01 : wzy00);
    wg[c] = wzy * (cx ? wx1 : wx0);
    q[c] = *(const uint4*)(basep + voff);
  }

  float acc[8] = {0.f, 0.f, 0.f, 0.f, 0.f, 0.f, 0.f, 0.f};
#pragma unroll
  for (int c = 0; c < 8; ++c) {
    const float wc = wg[c];
    const f16x8 h = __builtin_bit_cast(f16x8, q[c]);
#pragma unroll
    for (int j = 0; j < 8; ++j)
      acc[j] = fmaf(wc, (float)h[j], acc[j]);   // -> v_fma_mix_f32
  }

  // pack to 4 half2 words, butterfly over ks (lane bits 1..5)
  f16x2 p0 = pkrtz(acc[0], acc[1]);
  f16x2 p1 = pkrtz(acc[2], acc[3]);
  f16x2 p2 = pkrtz(acc[4], acc[5]);
  f16x2 p3 = pkrtz(acc[6], acc[7]);
#pragma unroll
  for (int msk = 2; msk <= 32; msk <<= 1) {
    p0 += __builtin_bit_cast(f16x2,
          __shfl_xor(__builtin_bit_cast(int, p0), msk, 64));
    p1 += __builtin_bit_cast(f16x2,
          __shfl_xor(__builtin_bit_cast(int, p1), msk, 64));
    p2 += __builtin_bit_cast(f16x2,
          __shfl_xor(__builtin_bit_cast(int, p2), msk, 64));
    p3 += __builtin_bit_cast(f16x2,
          __shfl_xor(__builtin_bit_cast(int, p3), msk, 64));
  }

  if (ks == 0) {
    uint4 o;
    o.x = __builtin_bit_cast(unsigned, p0);
    o.y = __builtin_bit_cast(unsigned, p1);
    o.z = __builtin_bit_cast(unsigned, p2);
    o.w = __builtin_bit_cast(unsigned, p3);
    *(uint4*)(y + (size_t)row * CC + g * CG + ch * 8) = o;
  }
}

extern "C" void kernel_launch(void* const* d_in, const int* in_sizes, int n_in,
                              void* d_out, int out_size, void* d_ws, size_t ws_size,
                              hipStream_t stream) {
  const float* f_in      = (const float*)d_in[0];
  const float* value_w   = (const float*)d_in[1];
  const float* value_b   = (const float*)d_in[2];
  const float* offmask_w = (const float*)d_in[3];
  const float* offmask_b = (const float*)d_in[4];
  const float* out_w     = (const float*)d_in[5];
  const float* out_b     = (const float*)d_in[6];
  float* out = (float*)d_out;

  // ws (f16 elems): wcat[992*128] | wout[128*128] | pxo[M*992] | y[M*128] | pbias f32[992]
  f16* wcat = (f16*)d_ws;
  f16* wout = wcat + (size_t)PXW * CC;
  f16* pxo  = wout + (size_t)CC * CC;
  f16* y    = pxo + (size_t)MM * PXW;
  float* pbias = (float*)(y + (size_t)MM * CC);

  build_wcat<<<(PXW * 32 + 255) / 256, 256, 0, stream>>>(value_w, offmask_w, wcat);
  build_bias<<<(PXW + 255) / 256, 256, 0, stream>>>(value_b, offmask_b, pbias);
  cvt_f2h<<<(CC * CC / 4 + 255) / 256, 256, 0, stream>>>(out_w, wout, CC * CC / 4);

  // proj GEMM: pxo[M,992] = f_in @ wcat^T + pbias   (A = f32, fused cast)
  gemm_k128<true, false, PXW><<<MM / 64, dim3(256), 0, stream>>>(
      f_in, wcat, pbias, (void*)pxo);
  // sampling core
  dcn_core<<<MM * GG / 4, dim3(256), 0, stream>>>(pxo, y);
  // out GEMM: d_out[M,128] f32 = y @ wout^T + out_b
  gemm_k128<false, true, CC><<<MM / 64, dim3(256), 0, stream>>>(
      y, wout, out_b, (void*)out);
}

// Round 5
// 360.412 us; speedup vs baseline: 1.1845x; 1.1845x over previous
//
#include <hip/hip_runtime.h>

// DCNv4 3D — round 5: LDS-tiled sampling core (no scattered gathers, no butterfly).
//  * proj GEMM writes value features to xg[g][n][32][32][32][16] (voxel = 32B
//    contiguous) and offsets/mask to om[row][G][K][4] f16.
//  * core: block = 4x4x4 tile x 1 group; stage 8^3 halo (x-padded [8][8][9])
//    + tile om into LDS; wave = 16 pos x 4 ch-dwords; k sequential; channels
//    lane-local -> zero cross-lane reduction.

typedef _Float16 f16;
typedef _Float16 f16x8 __attribute__((ext_vector_type(8)));
typedef _Float16 f16x4 __attribute__((ext_vector_type(4)));
typedef _Float16 f16x2 __attribute__((ext_vector_type(2)));
typedef float    f32x4 __attribute__((ext_vector_type(4)));

#define NB 2
#define DIM 32
#define CC 128
#define GG 8
#define CG 16
#define KPTS 27
#define LL (DIM*DIM*DIM)  // 32768
#define MM (NB*LL)        // 65536
#define OMD 864
#define PXW (CC + OMD)    // 992

__device__ __forceinline__ f16x2 pkrtz(float a, float b) {
  return __builtin_bit_cast(f16x2, __builtin_amdgcn_cvt_pkrtz(a, b));
}

// ---- build wcat [992,128] f16: value_w rows ++ permuted offmask_w rows ----
__global__ __launch_bounds__(256) void build_wcat(const float* __restrict__ vw,
                                                  const float* __restrict__ ow,
                                                  f16* __restrict__ wcat) {
  int t = blockIdx.x * 256 + threadIdx.x;
  if (t >= PXW * 32) return;
  int p = t >> 5, c4 = (t & 31) * 4;
  const float* src;
  if (p < CC) {
    src = vw + (size_t)p * CC;
  } else {
    int q = p - CC, g = q / 108, r = q % 108, k = r >> 2, j = r & 3;
    src = ow + (size_t)(g * 108 + (j < 3 ? k * 3 + j : 81 + k)) * CC;
  }
  float4 v = *(const float4*)(src + c4);
  f16x4 o = {(f16)v.x, (f16)v.y, (f16)v.z, (f16)v.w};
  *(f16x4*)(wcat + (size_t)p * CC + c4) = o;
}

__global__ __launch_bounds__(256) void build_bias(const float* __restrict__ vb,
                                                  const float* __restrict__ ob,
                                                  float* __restrict__ pbias) {
  int p = blockIdx.x * 256 + threadIdx.x;
  if (p >= PXW) return;
  float v;
  if (p < CC) v = vb[p];
  else {
    int q = p - CC, g = q / 108, r = q % 108, k = r >> 2, j = r & 3;
    v = ob[g * 108 + (j < 3 ? k * 3 + j : 81 + k)];
  }
  pbias[p] = v;
}

__global__ __launch_bounds__(256) void cvt_f2h(const float* __restrict__ in,
                                               f16* __restrict__ out, int n4) {
  int i = blockIdx.x * blockDim.x + threadIdx.x;
  if (i >= n4) return;
  float4 v = ((const float4*)in)[i];
  f16x4 o = {(f16)v.x, (f16)v.y, (f16)v.z, (f16)v.w};
  ((f16x4*)out)[i] = o;
}

// ---------------- GEMM: block = 4 waves x 64 rows, A reg-cached ----------
// MODE 0: proj  (A f32, NCOLS=992, write xg + om)
// MODE 1: out   (A f16, NCOLS=128, write f32 d_out)
template<int MODE>
__global__ __launch_bounds__(256) void gemm_k128(
    const void* __restrict__ Ain, const f16* __restrict__ B,
    const float* __restrict__ bias, f16* __restrict__ xg,
    f16* __restrict__ om, float* __restrict__ fout) {
  constexpr int NCOLS = MODE ? CC : PXW;
  const int w    = threadIdx.x >> 6;
  const int lane = threadIdx.x & 63;
  const int rowBase = blockIdx.x * 64 + w * 16;
  const int r  = lane & 15;
  const int kg = lane >> 4;

  f16x8 a[4];
  if (MODE == 0) {
    const float* A = (const float*)Ain + (size_t)(rowBase + r) * CC + kg * 8;
#pragma unroll
    for (int kk = 0; kk < 4; ++kk) {
      float4 lo = *(const float4*)(A + kk * 32);
      float4 hi = *(const float4*)(A + kk * 32 + 4);
      f16x8 t;
      t[0] = (f16)lo.x; t[1] = (f16)lo.y; t[2] = (f16)lo.z; t[3] = (f16)lo.w;
      t[4] = (f16)hi.x; t[5] = (f16)hi.y; t[6] = (f16)hi.z; t[7] = (f16)hi.w;
      a[kk] = t;
    }
  } else {
    const f16* A = (const f16*)Ain + (size_t)(rowBase + r) * CC + kg * 8;
#pragma unroll
    for (int kk = 0; kk < 4; ++kk) a[kk] = *(const f16x8*)(A + kk * 32);
  }

  for (int ct = 0; ct < NCOLS / 32; ++ct) {
    const int colBase = ct * 32;
    const f16* Bp = B + (unsigned)(colBase + r) * CC + kg * 8;
    f32x4 acc0 = {0.f, 0.f, 0.f, 0.f};
    f32x4 acc1 = {0.f, 0.f, 0.f, 0.f};
#pragma unroll
    for (int kk = 0; kk < 4; ++kk) {
      f16x8 b0 = *(const f16x8*)(Bp + kk * 32);
      f16x8 b1 = *(const f16x8*)(Bp + 16 * CC + kk * 32);
      acc0 = __builtin_amdgcn_mfma_f32_16x16x32_f16(a[kk], b0, acc0, 0, 0, 0);
      acc1 = __builtin_amdgcn_mfma_f32_16x16x32_f16(a[kk], b1, acc1, 0, 0, 0);
    }
    const int c0 = colBase + r;
    const int c1 = c0 + 16;
    const float bv0 = bias[c0];
    const float bv1 = bias[c1];
    const int drow = rowBase + kg * 4;
    if (MODE == 0) {
      if (ct < 4) {                     // value part -> xg (g0 = 2ct, g1 = 2ct+1)
        const int g0 = ct * 2, g1 = ct * 2 + 1;
#pragma unroll
        for (int i = 0; i < 4; ++i) {
          int row = drow + i;
          int nn = row >> 15, flat = row & (LL - 1);
          unsigned e0 = ((unsigned)((g0 * 2 + nn) << 15) + flat) * 16 + r;
          unsigned e1 = ((unsigned)((g1 * 2 + nn) << 15) + flat) * 16 + r;
          xg[e0] = (f16)(acc0[i] + bv0);
          xg[e1] = (f16)(acc1[i] + bv1);
        }
      } else {                          // offset/mask part -> om[row][864]
#pragma unroll
        for (int i = 0; i < 4; ++i) {
          unsigned ro = (unsigned)(drow + i) * OMD;
          om[ro + (c0 - CC)] = (f16)(acc0[i] + bv0);
          om[ro + (c1 - CC)] = (f16)(acc1[i] + bv1);
        }
      }
    } else {
#pragma unroll
      for (int i = 0; i < 4; ++i) {
        unsigned ro = (unsigned)(drow + i) * CC;
        fout[ro + c0] = acc0[i] + bv0;
        fout[ro + c1] = acc1[i] + bv1;
      }
    }
  }
}

// ---------------- DCNv4 sampling core v4 (LDS-tiled) ----------------
// block: 4^3 tile x 1 group. LDS: x halo [8z][8y][9x] voxels x 32B (pad x),
// om [64 pos][27] x 8B. wave = z-slice: lane = pl(16: py*4+px) * 4 + chd.
__global__ __launch_bounds__(256, 5) void dcn_core(const f16* __restrict__ xg,
                                                   const f16* __restrict__ om,
                                                   f16* __restrict__ y) {
  __shared__ uint2 ldsx[8 * 8 * 9 * 4];   // 18432 B
  __shared__ uint2 ldsom[64 * 27];        // 13824 B

  const int tid = threadIdx.x;
  int bid = blockIdx.x;
  const int g   = bid & 7;        bid >>= 3;
  const int n   = bid & 1;        bid >>= 1;
  const int tx0 = (bid & 7) * 4;  bid >>= 3;
  const int ty0 = (bid & 7) * 4;  bid >>= 3;
  const int tz0 = bid * 4;

  // ---- stage x halo (clamped coords; invalid corners get weight 0) ----
  const f16* xgb = xg + (((size_t)(g * 2 + n)) << 15) * 16;
#pragma unroll
  for (int it = 0; it < 2; ++it) {
    int v = tid + it * 256;
    int lz = v >> 6, ly = (v >> 3) & 7, lx = v & 7;
    int gz = min(max(tz0 - 2 + lz, 0), DIM - 1);
    int gy = min(max(ty0 - 2 + ly, 0), DIM - 1);
    int gx = min(max(tx0 - 2 + lx, 0), DIM - 1);
    const uint4* src = (const uint4*)(xgb + (size_t)(((gz << 5) + gy) * 32 + gx) * 16);
    uint4* dst = (uint4*)(ldsx + (size_t)(lz * 72 + ly * 9 + lx) * 4);
    dst[0] = src[0];
    dst[1] = src[1];
  }
  // ---- stage om: 64 pos x 27 x 8B (coalesced within pos) ----
  {
    const f16* omg = om + g * 108;
    for (int u = tid; u < 64 * 27; u += 256) {
      int pos = u / 27, k = u - pos * 27;
      int pz = pos >> 4, py = (pos >> 2) & 3, px = pos & 3;
      unsigned row = (unsigned)(n << 15) +
                     (((tz0 + pz) << 10) + ((ty0 + py) << 5) + (tx0 + px));
      ldsom[u] = *(const uint2*)(omg + (size_t)row * OMD + k * 4);
    }
  }
  __syncthreads();

  // ---- sampling ----
  const int pz  = tid >> 6;
  const int lane = tid & 63;
  const int pl  = lane >> 2;
  const int chd = lane & 3;
  const int py = pl >> 2, px = pl & 3;
  const int dz = tz0 + pz, dy = ty0 + py, dx = tx0 + px;
  const int posi = pz * 16 + pl;

  float dyf[3], dxf[3];
#pragma unroll
  for (int t = 0; t < 3; ++t) { dyf[t] = (float)(dy + t - 1); dxf[t] = (float)(dx + t - 1); }

  const uint2* omp = ldsom + posi * 27;
  float a0 = 0.f, a1 = 0.f, a2 = 0.f, a3 = 0.f;

  for (int kz = 0; kz < 3; ++kz) {
    const float bzf = (float)(dz + kz - 1);
    const uint2* omk = omp + kz * 9;
#pragma unroll
    for (int j = 0; j < 9; ++j) {
      const int kh = j / 3, kw = j % 3;
      uint2 o = omk[j];
      f16x2 o01 = __builtin_bit_cast(f16x2, o.x);
      f16x2 o23 = __builtin_bit_cast(f16x2, o.y);
      float pd = bzf + (float)o01[0];
      float ph = dyf[kh] + (float)o01[1];
      float pw = dxf[kw] + (float)o23[0];
      float m  = (float)o23[1];
      float fd = floorf(pd), fh = floorf(ph), fw = floorf(pw);
      float td = pd - fd, th = ph - fh, tw = pw - fw;
      int id = (int)fd, ih = (int)fh, iw = (int)fw;
      float wz0 = ((unsigned)id       < (unsigned)DIM) ? (1.f - td) * m : 0.f;
      float wz1 = ((unsigned)(id + 1) < (unsigned)DIM) ? td * m         : 0.f;
      float wy0 = ((unsigned)ih       < (unsigned)DIM) ? 1.f - th       : 0.f;
      float wy1 = ((unsigned)(ih + 1) < (unsigned)DIM) ? th             : 0.f;
      float wx0 = ((unsigned)iw       < (unsigned)DIM) ? 1.f - tw       : 0.f;
      float wx1 = ((unsigned)(iw + 1) < (unsigned)DIM) ? tw             : 0.f;
      // local lattice coords (|off|<1 keeps these in range; &7 = OOB safety)
      int lz0 = (id - tz0 + 2) & 7, lz1 = (lz0 + 1) & 7;
      int ly0 = (ih - ty0 + 2) & 7, ly1 = (ly0 + 1) & 7;
      int lx0 = (iw - tx0 + 2) & 7, lx1 = (lx0 + 1) & 7;
      int az0 = lz0 * 288, az1 = lz1 * 288;      // uint2-index strides
      int ay0 = ly0 * 36,  ay1 = ly1 * 36;
      int ax0 = lx0 * 4 + chd, ax1 = lx1 * 4 + chd;
      float wzy00 = wz0 * wy0, wzy01 = wz0 * wy1;
      float wzy10 = wz1 * wy0, wzy11 = wz1 * wy1;
#pragma unroll
      for (int c = 0; c < 8; ++c) {
        int idx = ((c & 4) ? az1 : az0) + ((c & 2) ? ay1 : ay0) + ((c & 1) ? ax1 : ax0);
        float wg = ((c & 4) ? ((c & 2) ? wzy11 : wzy10)
                            : ((c & 2) ? wzy01 : wzy00)) * ((c & 1) ? wx1 : wx0);
        uint2 d = ldsx[idx];
        f16x2 d0 = __builtin_bit_cast(f16x2, d.x);
        f16x2 d1 = __builtin_bit_cast(f16x2, d.y);
        a0 = fmaf(wg, (float)d0[0], a0);
        a1 = fmaf(wg, (float)d0[1], a1);
        a2 = fmaf(wg, (float)d1[0], a2);
        a3 = fmaf(wg, (float)d1[1], a3);
      }
    }
  }

  unsigned row = (unsigned)(n << 15) + ((dz << 10) + (dy << 5) + dx);
  uint2 st;
  st.x = __builtin_bit_cast(unsigned, pkrtz(a0, a1));
  st.y = __builtin_bit_cast(unsigned, pkrtz(a2, a3));
  *(uint2*)(y + (size_t)row * CC + g * CG + chd * 4) = st;
}

extern "C" void kernel_launch(void* const* d_in, const int* in_sizes, int n_in,
                              void* d_out, int out_size, void* d_ws, size_t ws_size,
                              hipStream_t stream) {
  const float* f_in      = (const float*)d_in[0];
  const float* value_w   = (const float*)d_in[1];
  const float* value_b   = (const float*)d_in[2];
  const float* offmask_w = (const float*)d_in[3];
  const float* offmask_b = (const float*)d_in[4];
  const float* out_w     = (const float*)d_in[5];
  const float* out_b     = (const float*)d_in[6];
  float* out = (float*)d_out;

  // ws (f16): wcat[992*128] | wout[128*128] | xg[G*N*L*16] | om[M*864] | y[M*128] | pbias f32
  f16* wcat = (f16*)d_ws;
  f16* wout = wcat + (size_t)PXW * CC;
  f16* xg   = wout + (size_t)CC * CC;
  f16* om   = xg + (size_t)GG * NB * LL * CG;
  f16* y    = om + (size_t)MM * OMD;
  float* pbias = (float*)(y + (size_t)MM * CC);

  build_wcat<<<(PXW * 32 + 255) / 256, 256, 0, stream>>>(value_w, offmask_w, wcat);
  build_bias<<<(PXW + 255) / 256, 256, 0, stream>>>(value_b, offmask_b, pbias);
  cvt_f2h<<<(CC * CC / 4 + 255) / 256, 256, 0, stream>>>(out_w, wout, CC * CC / 4);

  // proj GEMM -> xg + om
  gemm_k128<0><<<MM / 64, dim3(256), 0, stream>>>(f_in, wcat, pbias, xg, om, nullptr);
  // sampling core: 8 g x 2 n x 8^3 tiles
  dcn_core<<<GG * NB * 512, dim3(256), 0, stream>>>(xg, om, y);
  // out GEMM -> d_out f32
  gemm_k128<1><<<MM / 64, dim3(256), 0, stream>>>(y, wout, out_b, nullptr, nullptr, out);
}

// Round 6
// 285.903 us; speedup vs baseline: 1.4932x; 1.2606x over previous
//
#include <hip/hip_runtime.h>

// DCNv4 3D — round 6: core v5.
//  * zero-padded LDS halo (no validity cmp/cndmask chain; offsets med3-clamped)
//  * wave = 32 pos x 2 ch-halves; ds_read_b128 (8 ch / lane)
//  * packed f16 accumulation (v_pk_fma_f16), direct uint4 store
// GEMMs / layouts unchanged from round 5.

typedef _Float16 f16;
typedef _Float16 f16x8 __attribute__((ext_vector_type(8)));
typedef _Float16 f16x4 __attribute__((ext_vector_type(4)));
typedef _Float16 f16x2 __attribute__((ext_vector_type(2)));
typedef float    f32x4 __attribute__((ext_vector_type(4)));

#define NB 2
#define DIM 32
#define CC 128
#define GG 8
#define CG 16
#define KPTS 27
#define LL (DIM*DIM*DIM)  // 32768
#define MM (NB*LL)        // 65536
#define OMD 864
#define PXW (CC + OMD)    // 992

__device__ __forceinline__ f16x2 pkrtz(float a, float b) {
  return __builtin_bit_cast(f16x2, __builtin_amdgcn_cvt_pkrtz(a, b));
}

// ---- build wcat [992,128] f16: value_w rows ++ permuted offmask_w rows ----
__global__ __launch_bounds__(256) void build_wcat(const float* __restrict__ vw,
                                                  const float* __restrict__ ow,
                                                  f16* __restrict__ wcat) {
  int t = blockIdx.x * 256 + threadIdx.x;
  if (t >= PXW * 32) return;
  int p = t >> 5, c4 = (t & 31) * 4;
  const float* src;
  if (p < CC) {
    src = vw + (size_t)p * CC;
  } else {
    int q = p - CC, g = q / 108, r = q % 108, k = r >> 2, j = r & 3;
    src = ow + (size_t)(g * 108 + (j < 3 ? k * 3 + j : 81 + k)) * CC;
  }
  float4 v = *(const float4*)(src + c4);
  f16x4 o = {(f16)v.x, (f16)v.y, (f16)v.z, (f16)v.w};
  *(f16x4*)(wcat + (size_t)p * CC + c4) = o;
}

__global__ __launch_bounds__(256) void build_bias(const float* __restrict__ vb,
                                                  const float* __restrict__ ob,
                                                  float* __restrict__ pbias) {
  int p = blockIdx.x * 256 + threadIdx.x;
  if (p >= PXW) return;
  float v;
  if (p < CC) v = vb[p];
  else {
    int q = p - CC, g = q / 108, r = q % 108, k = r >> 2, j = r & 3;
    v = ob[g * 108 + (j < 3 ? k * 3 + j : 81 + k)];
  }
  pbias[p] = v;
}

__global__ __launch_bounds__(256) void cvt_f2h(const float* __restrict__ in,
                                               f16* __restrict__ out, int n4) {
  int i = blockIdx.x * blockDim.x + threadIdx.x;
  if (i >= n4) return;
  float4 v = ((const float4*)in)[i];
  f16x4 o = {(f16)v.x, (f16)v.y, (f16)v.z, (f16)v.w};
  ((f16x4*)out)[i] = o;
}

// ---------------- GEMM: block = 4 waves x 64 rows, A reg-cached ----------
template<int MODE>
__global__ __launch_bounds__(256) void gemm_k128(
    const void* __restrict__ Ain, const f16* __restrict__ B,
    const float* __restrict__ bias, f16* __restrict__ xg,
    f16* __restrict__ om, float* __restrict__ fout) {
  constexpr int NCOLS = MODE ? CC : PXW;
  const int w    = threadIdx.x >> 6;
  const int lane = threadIdx.x & 63;
  const int rowBase = blockIdx.x * 64 + w * 16;
  const int r  = lane & 15;
  const int kg = lane >> 4;

  f16x8 a[4];
  if (MODE == 0) {
    const float* A = (const float*)Ain + (size_t)(rowBase + r) * CC + kg * 8;
#pragma unroll
    for (int kk = 0; kk < 4; ++kk) {
      float4 lo = *(const float4*)(A + kk * 32);
      float4 hi = *(const float4*)(A + kk * 32 + 4);
      f16x8 t;
      t[0] = (f16)lo.x; t[1] = (f16)lo.y; t[2] = (f16)lo.z; t[3] = (f16)lo.w;
      t[4] = (f16)hi.x; t[5] = (f16)hi.y; t[6] = (f16)hi.z; t[7] = (f16)hi.w;
      a[kk] = t;
    }
  } else {
    const f16* A = (const f16*)Ain + (size_t)(rowBase + r) * CC + kg * 8;
#pragma unroll
    for (int kk = 0; kk < 4; ++kk) a[kk] = *(const f16x8*)(A + kk * 32);
  }

  for (int ct = 0; ct < NCOLS / 32; ++ct) {
    const int colBase = ct * 32;
    const f16* Bp = B + (unsigned)(colBase + r) * CC + kg * 8;
    f32x4 acc0 = {0.f, 0.f, 0.f, 0.f};
    f32x4 acc1 = {0.f, 0.f, 0.f, 0.f};
#pragma unroll
    for (int kk = 0; kk < 4; ++kk) {
      f16x8 b0 = *(const f16x8*)(Bp + kk * 32);
      f16x8 b1 = *(const f16x8*)(Bp + 16 * CC + kk * 32);
      acc0 = __builtin_amdgcn_mfma_f32_16x16x32_f16(a[kk], b0, acc0, 0, 0, 0);
      acc1 = __builtin_amdgcn_mfma_f32_16x16x32_f16(a[kk], b1, acc1, 0, 0, 0);
    }
    const int c0 = colBase + r;
    const int c1 = c0 + 16;
    const float bv0 = bias[c0];
    const float bv1 = bias[c1];
    const int drow = rowBase + kg * 4;
    if (MODE == 0) {
      if (ct < 4) {                     // value part -> xg
        const int g0 = ct * 2, g1 = ct * 2 + 1;
#pragma unroll
        for (int i = 0; i < 4; ++i) {
          int row = drow + i;
          int nn = row >> 15, flat = row & (LL - 1);
          unsigned e0 = ((unsigned)((g0 * 2 + nn) << 15) + flat) * 16 + r;
          unsigned e1 = ((unsigned)((g1 * 2 + nn) << 15) + flat) * 16 + r;
          xg[e0] = (f16)(acc0[i] + bv0);
          xg[e1] = (f16)(acc1[i] + bv1);
        }
      } else {                          // offset/mask part -> om[row][864]
#pragma unroll
        for (int i = 0; i < 4; ++i) {
          unsigned ro = (unsigned)(drow + i) * OMD;
          om[ro + (c0 - CC)] = (f16)(acc0[i] + bv0);
          om[ro + (c1 - CC)] = (f16)(acc1[i] + bv1);
        }
      }
    } else {
#pragma unroll
      for (int i = 0; i < 4; ++i) {
        unsigned ro = (unsigned)(drow + i) * CC;
        fout[ro + c0] = acc0[i] + bv0;
        fout[ro + c1] = acc1[i] + bv1;
      }
    }
  }
}

// ---------------- DCNv4 sampling core v5 ----------------
// block: 128 thr = 2 waves; one 4^3 tile x 1 group.
// LDS: zero-padded halo [8z][8y][9x] voxels x 2 uint4 (18432B) +
//      om [64 pos][27] uint2 (13824B).
// lane = pl(32 pos) * 2 + chd(2 ch-halves of 8 ch each).
__global__ __launch_bounds__(128) void dcn_core(const f16* __restrict__ xg,
                                                const f16* __restrict__ om,
                                                f16* __restrict__ y) {
  __shared__ uint4 ldsx[8 * 8 * 9 * 2];   // 18432 B
  __shared__ uint2 ldsom[64 * 27];        // 13824 B

  const int tid = threadIdx.x;
  int bid = blockIdx.x;
  const int g   = bid & 7;        bid >>= 3;
  const int n   = bid & 1;        bid >>= 1;
  const int tx0 = (bid & 7) * 4;  bid >>= 3;
  const int ty0 = (bid & 7) * 4;  bid >>= 3;
  const int tz0 = bid * 4;

  // ---- stage halo, zero-padded ----
  const f16* xgb = xg + (((size_t)(g * 2 + n)) << 15) * 16;
#pragma unroll
  for (int it = 0; it < 4; ++it) {
    int v = tid + it * 128;              // 512 voxels
    int lz = v >> 6, ly = (v >> 3) & 7, lx = v & 7;
    int gz = tz0 - 2 + lz, gy = ty0 - 2 + ly, gx = tx0 - 2 + lx;
    uint4 d0 = {0u, 0u, 0u, 0u}, d1 = {0u, 0u, 0u, 0u};
    if (((unsigned)gz < DIM) & ((unsigned)gy < DIM) & ((unsigned)gx < DIM)) {
      const uint4* src = (const uint4*)(xgb + (size_t)(((gz << 5) + gy) * 32 + gx) * 16);
      d0 = src[0];
      d1 = src[1];
    }
    uint4* dst = ldsx + (size_t)(lz * 72 + ly * 9 + lx) * 2;
    dst[0] = d0;
    dst[1] = d1;
  }
  // ---- stage om: 64 pos x 27 uint2 ----
  {
    const f16* omg = om + g * 108;
    for (int u = tid; u < 64 * 27; u += 128) {
      int pos = u / 27, k = u - pos * 27;
      int pz = pos >> 4, py = (pos >> 2) & 3, px = pos & 3;
      unsigned row = (unsigned)(n << 15) +
                     (((tz0 + pz) << 10) + ((ty0 + py) << 5) + (tx0 + px));
      ldsom[u] = *(const uint2*)(omg + (size_t)row * OMD + k * 4);
    }
  }
  __syncthreads();

  // ---- sampling ----
  const int wv   = tid >> 6;
  const int lane = tid & 63;
  const int pl   = lane >> 1;
  const int chd  = lane & 1;
  const int posi = wv * 32 + pl;                 // 0..63
  const int pz = posi >> 4, py = (posi >> 2) & 3, px = posi & 3;
  const int dz = tz0 + pz, dy = ty0 + py, dx = tx0 + px;

  const int zoff = tz0 - 2, yoff = ty0 - 2, xoff = tx0 - 2;
  float dyf[3], dxf[3];
#pragma unroll
  for (int t = 0; t < 3; ++t) { dyf[t] = (float)(dy + t - 1); dxf[t] = (float)(dx + t - 1); }

  const uint2* omp = ldsom + posi * 27;
  f16x2 acc0 = {(f16)0, (f16)0}, acc1 = acc0, acc2 = acc0, acc3 = acc0;
  const float CL = 0.99902344f;

  for (int kz = 0; kz < 3; ++kz) {
    const float bzf = (float)(dz + kz - 1);
    const uint2* omk = omp + kz * 9;
#pragma unroll
    for (int j = 0; j < 9; ++j) {
      const int kh = j / 3, kw = j % 3;
      uint2 o = omk[j];
      f16x2 o01 = __builtin_bit_cast(f16x2, o.x);
      f16x2 o23 = __builtin_bit_cast(f16x2, o.y);
      float od = fminf(fmaxf((float)o01[0], -CL), CL);
      float oh = fminf(fmaxf((float)o01[1], -CL), CL);
      float ow = fminf(fmaxf((float)o23[0], -CL), CL);
      float m  = (float)o23[1];
      float pd = bzf + od;
      float ph = dyf[kh] + oh;
      float pw = dxf[kw] + ow;
      float fd = floorf(pd), fh = floorf(ph), fw = floorf(pw);
      float td = pd - fd, th = ph - fh, tw = pw - fw;
      int id = (int)fd, ih = (int)fh, iw = (int)fw;
      // zero-padded halo: no validity checks needed
      float wz0 = (1.f - td) * m, wz1 = td * m;
      float wy0 = 1.f - th,        wy1 = th;
      float wx0 = 1.f - tw,        wx1 = tw;
      int az0 = (id - zoff) * 144, az1 = az0 + 144;   // uint4-index strides
      int ay0 = (ih - yoff) * 18,  ay1 = ay0 + 18;
      int ax0 = (iw - xoff) * 2 + chd, ax1 = ax0 + 2;
      float wzy00 = wz0 * wy0, wzy01 = wz0 * wy1;
      float wzy10 = wz1 * wy0, wzy11 = wz1 * wy1;
#pragma unroll
      for (int c = 0; c < 8; ++c) {
        int idx = ((c & 4) ? az1 : az0) + ((c & 2) ? ay1 : ay0) + ((c & 1) ? ax1 : ax0);
        float wg = ((c & 4) ? ((c & 2) ? wzy11 : wzy10)
                            : ((c & 2) ? wzy01 : wzy00)) * ((c & 1) ? wx1 : wx0);
        uint4 q = ldsx[idx];
        f16x2 w2 = pkrtz(wg, wg);
        acc0 = __builtin_bit_cast(f16x2, q.x) * w2 + acc0;
        acc1 = __builtin_bit_cast(f16x2, q.y) * w2 + acc1;
        acc2 = __builtin_bit_cast(f16x2, q.z) * w2 + acc2;
        acc3 = __builtin_bit_cast(f16x2, q.w) * w2 + acc3;
      }
    }
  }

  unsigned row = (unsigned)(n << 15) + ((dz << 10) + (dy << 5) + dx);
  uint4 st;
  st.x = __builtin_bit_cast(unsigned, acc0);
  st.y = __builtin_bit_cast(unsigned, acc1);
  st.z = __builtin_bit_cast(unsigned, acc2);
  st.w = __builtin_bit_cast(unsigned, acc3);
  *(uint4*)(y + (size_t)row * CC + g * CG + chd * 8) = st;
}

extern "C" void kernel_launch(void* const* d_in, const int* in_sizes, int n_in,
                              void* d_out, int out_size, void* d_ws, size_t ws_size,
                              hipStream_t stream) {
  const float* f_in      = (const float*)d_in[0];
  const float* value_w   = (const float*)d_in[1];
  const float* value_b   = (const float*)d_in[2];
  const float* offmask_w = (const float*)d_in[3];
  const float* offmask_b = (const float*)d_in[4];
  const float* out_w     = (const float*)d_in[5];
  const float* out_b     = (const float*)d_in[6];
  float* out = (float*)d_out;

  // ws (f16): wcat[992*128] | wout[128*128] | xg[G*N*L*16] | om[M*864] | y[M*128] | pbias f32
  f16* wcat = (f16*)d_ws;
  f16* wout = wcat + (size_t)PXW * CC;
  f16* xg   = wout + (size_t)CC * CC;
  f16* om   = xg + (size_t)GG * NB * LL * CG;
  f16* y    = om + (size_t)MM * OMD;
  float* pbias = (float*)(y + (size_t)MM * CC);

  build_wcat<<<(PXW * 32 + 255) / 256, 256, 0, stream>>>(value_w, offmask_w, wcat);
  build_bias<<<(PXW + 255) / 256, 256, 0, stream>>>(value_b, offmask_b, pbias);
  cvt_f2h<<<(CC * CC / 4 + 255) / 256, 256, 0, stream>>>(out_w, wout, CC * CC / 4);

  // proj GEMM -> xg + om
  gemm_k128<0><<<MM / 64, dim3(256), 0, stream>>>(f_in, wcat, pbias, xg, om, nullptr);
  // sampling core: 8 g x 2 n x 8^3 tiles, 128-thread blocks
  dcn_core<<<GG * NB * 512, dim3(128), 0, stream>>>(xg, om, y);
  // out GEMM -> d_out f32
  gemm_k128<1><<<MM / 64, dim3(256), 0, stream>>>(y, wout, out_b, nullptr, nullptr, out);
}